// Round 3
// baseline (275.950 us; speedup 1.0000x reference)
//
#include <hip/hip_runtime.h>

#define NQ 6
#define HID 32
#define SNAPS 16
#define BATCH 1024
#define FSTRIDE 24       // floats per feature vector
#define FTOT 384         // 16 * 24
// K2 LDS geometry: stride 24 floats (16B-aligned, <=2-way bank conflicts = free)
#define KSTR 24
#define KF   192         // per-f block: 8 cols/rows x 24

__device__ __forceinline__ float sigm_f(float x) { return 1.0f / (1.0f + __expf(-x)); }
// tanh(x) = 1 - 2/(exp(2x)+1)
__device__ __forceinline__ float tanh_f(float x) { return 1.0f - 2.0f / (__expf(2.0f * x) + 1.0f); }

__device__ __forceinline__ void rc_entry(float g, float b0, float b1, float b2,
                                         int i, int j, float& re, float& im) {
    // rc = (I + 3*shadow*B)/2, B = b0*sx + b1*sy + b2*sz ; g = 1.5*shadow
    if (i == j) { re = 0.5f + (i ? -g * b2 : g * b2); im = 0.0f; }
    else        { re = g * b0;  im = (i ? g * b1 : -g * b1); }
}

// ============================ K1: LSTM chain ============================
// One wave per batch element. No __syncthreads. Lane l owns gate rows l and l+64.
__global__ __launch_bounds__(256)
void lstm_kernel(const float* __restrict__ snapshot,   // (B,6)
                 const float* __restrict__ bcv,        // (B,6,3)
                 const float* __restrict__ h0,         // (B,32)
                 const float* __restrict__ c0,         // (B,32)
                 const float* __restrict__ W_ih,       // (128,24)
                 const float* __restrict__ W_hh,       // (128,32)
                 const float* __restrict__ b_ih,       // (128)
                 const float* __restrict__ b_hh,       // (128)
                 const float* __restrict__ Wp,         // (6,32,3)
                 const float* __restrict__ bp,         // (6,3)
                 float* __restrict__ feats,            // ws: (B,16,24)
                 float* __restrict__ out_tail)         // (B,6,3)
{
    __shared__ __align__(16) float sxh[4][64];   // per wave: [0..23]=x, [32..63]=h
    const int w = threadIdx.x >> 6;
    const int l = threadIdx.x & 63;
    const int b = blockIdx.x * 4 + w;
    float* sx = &sxh[w][0];
    float* sh = &sxh[w][32];

    // gate-row weights in VGPRs: rows r0 = l (i|f), r1 = l+64 (g|o)
    float4 wih0[6], wih1[6], whh0[8], whh1[8];
    {
        const float4* p0 = (const float4*)(W_ih + l * 24);
        const float4* p1 = (const float4*)(W_ih + (l + 64) * 24);
        #pragma unroll
        for (int k = 0; k < 6; ++k) { wih0[k] = p0[k]; wih1[k] = p1[k]; }
        const float4* q0 = (const float4*)(W_hh + l * 32);
        const float4* q1 = (const float4*)(W_hh + (l + 64) * 32);
        #pragma unroll
        for (int k = 0; k < 8; ++k) { whh0[k] = q0[k]; whh1[k] = q1[k]; }
    }
    const float bias0 = b_ih[l] + b_hh[l];
    const float bias1 = b_ih[l + 64] + b_hh[l + 64];

    // projection weights (transposed rows) for lanes 0..17
    float wp[32];
    float bpv = 0.0f;
    if (l < 18) {
        int q = l / 3, s = l - 3 * q;
        #pragma unroll
        for (int k = 0; k < 32; ++k) wp[k] = Wp[q * 96 + 3 * k + s];
        bpv = bp[l];
    }

    float c = 0.0f;
    if (l < 32) { c = c0[b * 32 + l]; sh[l] = h0[b * 32 + l]; }
    if (l < 24) {
        float v = (l < 6) ? snapshot[b * 6 + l] : bcv[b * 18 + (l - 6)];
        sx[l] = v;
        feats[b * FTOT + l] = v;    // feature 0
    }
    __builtin_amdgcn_wave_barrier();

    for (int step = 0; step < SNAPS - 1; ++step) {
        // ---- gates: g0 = row l, g1 = row l+64 (broadcast LDS reads of x,h) ----
        const float4* x4 = (const float4*)sx;
        const float4* h4 = (const float4*)sh;
        float g0 = bias0, g1 = bias1, g0b = 0.0f, g1b = 0.0f;
        #pragma unroll
        for (int k = 0; k < 6; ++k) {
            float4 xq = x4[k];
            g0  += xq.x * wih0[k].x + xq.y * wih0[k].y;
            g0b += xq.z * wih0[k].z + xq.w * wih0[k].w;
            g1  += xq.x * wih1[k].x + xq.y * wih1[k].y;
            g1b += xq.z * wih1[k].z + xq.w * wih1[k].w;
        }
        #pragma unroll
        for (int k = 0; k < 8; ++k) {
            float4 hq = h4[k];
            g0  += hq.x * whh0[k].x + hq.y * whh0[k].y;
            g0b += hq.z * whh0[k].z + hq.w * whh0[k].w;
            g1  += hq.x * whh1[k].x + hq.y * whh1[k].y;
            g1b += hq.z * whh1[k].z + hq.w * whh1[k].w;
        }
        g0 += g0b; g1 += g1b;

        // ---- activation: lanes<32 hold (i,g); lanes>=32 hold (f,o) ----
        float gf = __shfl_xor(g0, 32);
        float go = __shfl_xor(g1, 32);
        if (l < 32) {
            c = sigm_f(gf) * c + sigm_f(g0) * tanh_f(g1);
            sh[l] = sigm_f(go) * tanh_f(c);
        }
        __builtin_amdgcn_wave_barrier();

        // ---- projection: lanes 0..17 compute logit[3q+s] ----
        float logit = bpv;
        const float4* h4b = (const float4*)sh;
        #pragma unroll
        for (int k = 0; k < 8; ++k) {
            float4 hq = h4b[k];
            logit += hq.x * wp[4 * k] + hq.y * wp[4 * k + 1]
                   + hq.z * wp[4 * k + 2] + hq.w * wp[4 * k + 3];
        }

        // ---- softmax + feature write: lanes 0..5 ----
        int q3 = 3 * (l < 6 ? l : 0);
        float l0 = __shfl(logit, q3), l1 = __shfl(logit, q3 + 1), l2 = __shfl(logit, q3 + 2);
        if (l < 6) {
            float m = fmaxf(l0, fmaxf(l1, l2));
            float e0 = __expf(l0 - m), e1 = __expf(l1 - m), e2 = __expf(l2 - m);
            float inv = 1.0f / (e0 + e1 + e2);
            float p0 = e0 * inv, p1 = e1 * inv, p2 = e2 * inv;
            float snap = p0 * p0 + p1 * p1 + p2 * p2;   // tr(M rho Mdag)=sum p^2 (rho unused)
            sx[l] = snap;
            sx[6 + 3 * l]     = p0;
            sx[6 + 3 * l + 1] = p1;
            sx[6 + 3 * l + 2] = p2;
            float* fd = feats + b * FTOT + (step + 1) * FSTRIDE;
            fd[l] = snap;
            fd[6 + 3 * l]     = p0;
            fd[6 + 3 * l + 1] = p1;
            fd[6 + 3 * l + 2] = p2;
            if (step == SNAPS - 2) {
                float* ot = out_tail + b * 18 + 3 * l;
                ot[0] = p0; ot[1] = p1; ot[2] = p2;
            }
        }
        __builtin_amdgcn_wave_barrier();
    }
}

// ============================ K2: reconstruction ============================
// Block per batch. KA: transposed, even/odd-row grouped -> 2 x b128 per f.
// KB: row-major -> 2 x b128 per f. Output: 8 x dwordx4 stores per thread.
__global__ __launch_bounds__(256, 4)
void recon_kernel(const float* __restrict__ feats, float* __restrict__ out)
{
    __shared__ __align__(16) float sK[2 * 16 * KF + FTOT];
    float* sKA = sK;                 // 3072
    float* sKB = sK + 16 * KF;       // 3072
    float* sf  = sK + 32 * KF;       // 384
    const int b = blockIdx.x;
    const int t = threadIdx.x;

    sf[t] = feats[b * FTOT + t];
    if (t < 128) sf[256 + t] = feats[b * FTOT + 256 + t];
    __syncthreads();

    // ---- build KA/KB: 2048 entries, 8 per thread ----
    for (int n = t; n < 2048; n += 256) {
        int f = n >> 7, r = n & 127;
        int half = r >> 6, a = r & 63;
        const float* fx = &sf[f * FSTRIDE];
        int i0 = (a >> 5) & 1, i1 = (a >> 4) & 1, i2 = (a >> 3) & 1;
        int j0 = (a >> 2) & 1, j1 = (a >> 1) & 1, j2 = a & 1;
        int q = 3 * half;
        float g0 = 1.5f * fx[q], g1 = 1.5f * fx[q + 1], g2 = 1.5f * fx[q + 2];
        const float* bb = fx + 6 + 3 * q;
        float r0, m0, r1, m1, r2, m2;
        rc_entry(g0, bb[0], bb[1], bb[2], i0, j0, r0, m0);
        rc_entry(g1, bb[3], bb[4], bb[5], i1, j1, r1, m1);
        rc_entry(g2, bb[6], bb[7], bb[8], i2, j2, r2, m2);
        float pr = r0 * r1 - m0 * m1, pi = r0 * m1 + m0 * r1;
        float qr = pr * r2 - pi * m2, qi = pr * m2 + pi * r2;
        int row = a >> 3, col = a & 7;
        if (half == 0) {
            // col-major, rows grouped by parity: even rows at [0..7], odd at [8..15]
            int off = f * KF + col * KSTR + ((row & 1) ? (7 + row) : row);
            sKA[off] = qr; sKA[off + 1] = qi;
        } else {
            int off = f * KF + row * KSTR + 2 * col;
            sKB[off] = qr; sKB[off + 1] = qi;
        }
    }
    __syncthreads();

    // ---- accumulate: out[i][j] = (1/16) sum_f KA[i>>3][j>>3] * KB[i&7][j&7]
    // thread t: u=t&15, v=t>>4; i = v+16e (e<4), j = 4u+d (d<4)
    const int u = t & 15, v = t >> 4;
    const float* baseA = sKA + (u >> 1) * KSTR + 8 * (v >> 3);   // col jA, parity group
    const float* baseB = sKB + (v & 7) * KSTR + 8 * (u & 1);     // row iB, col group
    float accr[4][4], acci[4][4];
    #pragma unroll
    for (int e = 0; e < 4; ++e)
        #pragma unroll
        for (int d = 0; d < 4; ++d) { accr[e][d] = 0.0f; acci[e][d] = 0.0f; }

    #pragma unroll
    for (int f = 0; f < SNAPS; ++f) {
        float4 A0 = *(const float4*)(baseA + f * KF);
        float4 A1 = *(const float4*)(baseA + f * KF + 4);
        float4 B0 = *(const float4*)(baseB + f * KF);
        float4 B1 = *(const float4*)(baseB + f * KF + 4);
        float ar[4] = {A0.x, A0.z, A1.x, A1.z};    // iA = 2e + (v>>3)
        float ai[4] = {A0.y, A0.w, A1.y, A1.w};
        float br[4] = {B0.x, B0.z, B1.x, B1.z};    // jB = 4(u&1) + d
        float bi[4] = {B0.y, B0.w, B1.y, B1.w};
        #pragma unroll
        for (int e = 0; e < 4; ++e)
            #pragma unroll
            for (int d = 0; d < 4; ++d) {
                accr[e][d] += ar[e] * br[d] - ai[e] * bi[d];
                acci[e][d] += ar[e] * bi[d] + ai[e] * br[d];
            }
    }

    const float s = 1.0f / 16.0f;
    float* outb = out + (size_t)b * 8192;
    #pragma unroll
    for (int e = 0; e < 4; ++e) {
        int i = v + 16 * e;
        float4 r4 = make_float4(accr[e][0] * s, accr[e][1] * s, accr[e][2] * s, accr[e][3] * s);
        float4 i4 = make_float4(acci[e][0] * s, acci[e][1] * s, acci[e][2] * s, acci[e][3] * s);
        *(float4*)(outb + i * 64 + 4 * u) = r4;
        *(float4*)(outb + 4096 + i * 64 + 4 * u) = i4;
    }
}

extern "C" void kernel_launch(void* const* d_in, const int* in_sizes, int n_in,
                              void* d_out, int out_size, void* d_ws, size_t ws_size,
                              hipStream_t stream) {
    const float* snapshot = (const float*)d_in[0];
    const float* bcv      = (const float*)d_in[1];
    // d_in[2] = rho — unused: tr(M rho M^dag) = (sum_s p_s^2) tr(rho), tr(rho)=1
    const float* h0       = (const float*)d_in[3];
    const float* c0       = (const float*)d_in[4];
    const float* W_ih     = (const float*)d_in[5];
    const float* W_hh     = (const float*)d_in[6];
    const float* b_ih     = (const float*)d_in[7];
    const float* b_hh     = (const float*)d_in[8];
    const float* Wp       = (const float*)d_in[9];
    const float* bp       = (const float*)d_in[10];
    // d_in[11], d_in[12] = basis_r, basis_i — folded into rc_entry
    float* out   = (float*)d_out;
    float* featw = (float*)d_ws;     // 1024*384*4 = 1.57 MB scratch

    lstm_kernel<<<BATCH / 4, 256, 0, stream>>>(
        snapshot, bcv, h0, c0, W_ih, W_hh, b_ih, b_hh, Wp, bp,
        featw, out + (size_t)BATCH * 8192);
    recon_kernel<<<BATCH, 256, 0, stream>>>(featw, out);
}

// Round 5
// 134.417 us; speedup vs baseline: 2.0529x; 2.0529x over previous
//
#include <hip/hip_runtime.h>

#define NQ 6
#define HID 32
#define SNAPS 16
#define BATCH 1024
#define FSTRIDE 24       // floats per feature vector
#define FTOT 384         // 16 * 24
// K2 LDS geometry: stride 24 floats (16B-aligned, <=2-way bank conflicts = free)
#define KSTR 24
#define KF   192         // per-f block: 8 cols/rows x 24
#define WSTR 416         // K1 per-wave LDS: 384 feats + 32 h (1664B, 16B-aligned)

typedef float vfloat4 __attribute__((ext_vector_type(4)));   // native vec for nontemporal builtin

__device__ __forceinline__ float sigm_f(float x) { return 1.0f / (1.0f + __expf(-x)); }
// tanh(x) = 1 - 2/(exp(2x)+1)
__device__ __forceinline__ float tanh_f(float x) { return 1.0f - 2.0f / (__expf(2.0f * x) + 1.0f); }

__device__ __forceinline__ void rc_entry(float g, float b0, float b1, float b2,
                                         int i, int j, float& re, float& im) {
    // rc = (I + 3*shadow*B)/2, B = b0*sx + b1*sy + b2*sz ; g = 1.5*shadow
    if (i == j) { re = 0.5f + (i ? -g * b2 : g * b2); im = 0.0f; }
    else        { re = g * b0;  im = (i ? g * b1 : -g * b1); }
}

// ============================ K1: LSTM chain ============================
// One wave per batch element. No __syncthreads. Lane l owns gate rows l and l+64.
// Features accumulate in per-wave LDS; one coalesced flush at the end.
__global__ __launch_bounds__(256, 1)
void lstm_kernel(const float* __restrict__ snapshot,   // (B,6)
                 const float* __restrict__ bcv,        // (B,6,3)
                 const float* __restrict__ h0,         // (B,32)
                 const float* __restrict__ c0,         // (B,32)
                 const float* __restrict__ W_ih,       // (128,24)
                 const float* __restrict__ W_hh,       // (128,32)
                 const float* __restrict__ b_ih,       // (128)
                 const float* __restrict__ b_hh,       // (128)
                 const float* __restrict__ Wp,         // (6,32,3)
                 const float* __restrict__ bp,         // (6,3)
                 float* __restrict__ feats,            // ws: (B,16,24)
                 float* __restrict__ out_tail)         // (B,6,3)
{
    __shared__ __align__(16) float sbuf[4 * WSTR];
    const int w = threadIdx.x >> 6;
    const int l = threadIdx.x & 63;
    const int b = blockIdx.x * 4 + w;
    float* feat = sbuf + w * WSTR;       // [0..383] features, [384..415] h
    float* sh   = feat + 384;

    // gate-row weights in VGPRs: rows r0 = l (i|f), r1 = l+64 (g|o)
    float4 wih0[6], wih1[6], whh0[8], whh1[8];
    {
        const float4* p0 = (const float4*)(W_ih + l * 24);
        const float4* p1 = (const float4*)(W_ih + (l + 64) * 24);
        #pragma unroll
        for (int k = 0; k < 6; ++k) { wih0[k] = p0[k]; wih1[k] = p1[k]; }
        const float4* q0 = (const float4*)(W_hh + l * 32);
        const float4* q1 = (const float4*)(W_hh + (l + 64) * 32);
        #pragma unroll
        for (int k = 0; k < 8; ++k) { whh0[k] = q0[k]; whh1[k] = q1[k]; }
    }
    const float bias0 = b_ih[l] + b_hh[l];
    const float bias1 = b_ih[l + 64] + b_hh[l + 64];

    // projection weights (transposed rows) for lanes 0..17
    float wp[32];
    float bpv = 0.0f;
    if (l < 18) {
        int q = l / 3, s = l - 3 * q;
        #pragma unroll
        for (int k = 0; k < 32; ++k) wp[k] = Wp[q * 96 + 3 * k + s];
        bpv = bp[l];
    }

    float c = 0.0f;
    if (l < 32) { c = c0[b * 32 + l]; sh[l] = h0[b * 32 + l]; }
    if (l < 24) feat[l] = (l < 6) ? snapshot[b * 6 + l] : bcv[b * 18 + (l - 6)];
    __builtin_amdgcn_wave_barrier();

    for (int step = 0; step < SNAPS - 1; ++step) {
        // ---- gates: g0 = row l, g1 = row l+64 (broadcast LDS reads of x,h) ----
        const float4* x4 = (const float4*)(feat + step * FSTRIDE);
        const float4* h4 = (const float4*)sh;
        float g0 = bias0, g1 = bias1, g0b = 0.0f, g1b = 0.0f;
        #pragma unroll
        for (int k = 0; k < 6; ++k) {
            float4 xq = x4[k];
            g0  += xq.x * wih0[k].x + xq.y * wih0[k].y;
            g0b += xq.z * wih0[k].z + xq.w * wih0[k].w;
            g1  += xq.x * wih1[k].x + xq.y * wih1[k].y;
            g1b += xq.z * wih1[k].z + xq.w * wih1[k].w;
        }
        #pragma unroll
        for (int k = 0; k < 8; ++k) {
            float4 hq = h4[k];
            g0  += hq.x * whh0[k].x + hq.y * whh0[k].y;
            g0b += hq.z * whh0[k].z + hq.w * whh0[k].w;
            g1  += hq.x * whh1[k].x + hq.y * whh1[k].y;
            g1b += hq.z * whh1[k].z + hq.w * whh1[k].w;
        }
        g0 += g0b; g1 += g1b;

        // ---- activation: lanes<32 hold (i,g); lanes>=32 hold (f,o) ----
        float gf = __shfl_xor(g0, 32);
        float go = __shfl_xor(g1, 32);
        if (l < 32) {
            c = sigm_f(gf) * c + sigm_f(g0) * tanh_f(g1);
            sh[l] = sigm_f(go) * tanh_f(c);
        }
        __builtin_amdgcn_wave_barrier();

        // ---- projection: lanes 0..17 compute logit[3q+s] ----
        float logit = bpv;
        const float4* h4b = (const float4*)sh;
        #pragma unroll
        for (int k = 0; k < 8; ++k) {
            float4 hq = h4b[k];
            logit += hq.x * wp[4 * k] + hq.y * wp[4 * k + 1]
                   + hq.z * wp[4 * k + 2] + hq.w * wp[4 * k + 3];
        }

        // ---- softmax + feature write (LDS only): lanes 0..5 ----
        int q3 = 3 * (l < 6 ? l : 0);
        float l0 = __shfl(logit, q3), l1 = __shfl(logit, q3 + 1), l2 = __shfl(logit, q3 + 2);
        if (l < 6) {
            float m = fmaxf(l0, fmaxf(l1, l2));
            float e0 = __expf(l0 - m), e1 = __expf(l1 - m), e2 = __expf(l2 - m);
            float inv = 1.0f / (e0 + e1 + e2);
            float p0 = e0 * inv, p1 = e1 * inv, p2 = e2 * inv;
            float snap = p0 * p0 + p1 * p1 + p2 * p2;   // tr(M rho Mdag)=sum p^2 (rho unused)
            float* fd = feat + (step + 1) * FSTRIDE;
            fd[l] = snap;
            fd[6 + 3 * l]     = p0;
            fd[6 + 3 * l + 1] = p1;
            fd[6 + 3 * l + 2] = p2;
        }
        __builtin_amdgcn_wave_barrier();
    }

    // ---- coalesced flush of all 16 features + tail output ----
    #pragma unroll
    for (int k = 0; k < 6; ++k)
        feats[b * FTOT + k * 64 + l] = feat[k * 64 + l];
    if (l < 18) out_tail[b * 18 + l] = feat[15 * FSTRIDE + 6 + l];
}

// ============================ K2: reconstruction ============================
// Block per batch. KA: transposed, even/odd-row grouped -> 2 x b128 per f.
// KB: row-major -> 2 x b128 per f. Output: 8 x dwordx4 nontemporal stores.
__global__ __launch_bounds__(256, 2)   // (256,4) caps VGPR at 64 -> spills (R3); 2 -> ~128 cap
void recon_kernel(const float* __restrict__ feats, float* __restrict__ out)
{
    __shared__ __align__(16) float sK[2 * 16 * KF + FTOT];
    float* sKA = sK;                 // 3072
    float* sKB = sK + 16 * KF;       // 3072
    float* sf  = sK + 32 * KF;       // 384
    const int b = blockIdx.x;
    const int t = threadIdx.x;

    sf[t] = feats[b * FTOT + t];
    if (t < 128) sf[256 + t] = feats[b * FTOT + 256 + t];
    __syncthreads();

    // ---- build KA/KB: 2048 entries, 8 per thread ----
    for (int n = t; n < 2048; n += 256) {
        int f = n >> 7, r = n & 127;
        int half = r >> 6, a = r & 63;
        const float* fx = &sf[f * FSTRIDE];
        int i0 = (a >> 5) & 1, i1 = (a >> 4) & 1, i2 = (a >> 3) & 1;
        int j0 = (a >> 2) & 1, j1 = (a >> 1) & 1, j2 = a & 1;
        int q = 3 * half;
        float g0 = 1.5f * fx[q], g1 = 1.5f * fx[q + 1], g2 = 1.5f * fx[q + 2];
        const float* bb = fx + 6 + 3 * q;
        float r0, m0, r1, m1, r2, m2;
        rc_entry(g0, bb[0], bb[1], bb[2], i0, j0, r0, m0);
        rc_entry(g1, bb[3], bb[4], bb[5], i1, j1, r1, m1);
        rc_entry(g2, bb[6], bb[7], bb[8], i2, j2, r2, m2);
        float pr = r0 * r1 - m0 * m1, pi = r0 * m1 + m0 * r1;
        float qr = pr * r2 - pi * m2, qi = pr * m2 + pi * r2;
        int row = a >> 3, col = a & 7;
        if (half == 0) {
            // col-major, rows grouped by parity: even rows at [0..7], odd at [8..15]
            int off = f * KF + col * KSTR + ((row & 1) ? (7 + row) : row);
            sKA[off] = qr; sKA[off + 1] = qi;
        } else {
            int off = f * KF + row * KSTR + 2 * col;
            sKB[off] = qr; sKB[off + 1] = qi;
        }
    }
    __syncthreads();

    // ---- accumulate: out[i][j] = (1/16) sum_f KA[i>>3][j>>3] * KB[i&7][j&7]
    // thread t: u=t&15, v=t>>4; i = v+16e (e<4), j = 4u+d (d<4)
    const int u = t & 15, v = t >> 4;
    const float* baseA = sKA + (u >> 1) * KSTR + 8 * (v >> 3);   // col jA, parity group
    const float* baseB = sKB + (v & 7) * KSTR + 8 * (u & 1);     // row iB, col group
    float accr[4][4], acci[4][4];
    #pragma unroll
    for (int e = 0; e < 4; ++e)
        #pragma unroll
        for (int d = 0; d < 4; ++d) { accr[e][d] = 0.0f; acci[e][d] = 0.0f; }

    #pragma unroll 2   // keep hoisted LDS loads within the 128-VGPR budget (no scratch!)
    for (int f = 0; f < SNAPS; ++f) {
        float4 A0 = *(const float4*)(baseA + f * KF);
        float4 A1 = *(const float4*)(baseA + f * KF + 4);
        float4 B0 = *(const float4*)(baseB + f * KF);
        float4 B1 = *(const float4*)(baseB + f * KF + 4);
        float ar[4] = {A0.x, A0.z, A1.x, A1.z};    // iA = 2e + (v>>3)
        float ai[4] = {A0.y, A0.w, A1.y, A1.w};
        float br[4] = {B0.x, B0.z, B1.x, B1.z};    // jB = 4(u&1) + d
        float bi[4] = {B0.y, B0.w, B1.y, B1.w};
        #pragma unroll
        for (int e = 0; e < 4; ++e)
            #pragma unroll
            for (int d = 0; d < 4; ++d) {
                accr[e][d] += ar[e] * br[d] - ai[e] * bi[d];
                acci[e][d] += ar[e] * bi[d] + ai[e] * br[d];
            }
    }

    const float s = 1.0f / 16.0f;
    float* outb = out + (size_t)b * 8192;
    #pragma unroll
    for (int e = 0; e < 4; ++e) {
        int i = v + 16 * e;
        vfloat4 r4 = { accr[e][0] * s, accr[e][1] * s, accr[e][2] * s, accr[e][3] * s };
        vfloat4 i4 = { acci[e][0] * s, acci[e][1] * s, acci[e][2] * s, acci[e][3] * s };
        __builtin_nontemporal_store(r4, (vfloat4*)(outb + i * 64 + 4 * u));
        __builtin_nontemporal_store(i4, (vfloat4*)(outb + 4096 + i * 64 + 4 * u));
    }
}

extern "C" void kernel_launch(void* const* d_in, const int* in_sizes, int n_in,
                              void* d_out, int out_size, void* d_ws, size_t ws_size,
                              hipStream_t stream) {
    const float* snapshot = (const float*)d_in[0];
    const float* bcv      = (const float*)d_in[1];
    // d_in[2] = rho — unused: tr(M rho M^dag) = (sum_s p_s^2) tr(rho), tr(rho)=1
    const float* h0       = (const float*)d_in[3];
    const float* c0       = (const float*)d_in[4];
    const float* W_ih     = (const float*)d_in[5];
    const float* W_hh     = (const float*)d_in[6];
    const float* b_ih     = (const float*)d_in[7];
    const float* b_hh     = (const float*)d_in[8];
    const float* Wp       = (const float*)d_in[9];
    const float* bp       = (const float*)d_in[10];
    // d_in[11], d_in[12] = basis_r, basis_i — folded into rc_entry
    float* out   = (float*)d_out;
    float* featw = (float*)d_ws;     // 1024*384*4 = 1.57 MB scratch

    lstm_kernel<<<BATCH / 4, 256, 0, stream>>>(
        snapshot, bcv, h0, c0, W_ih, W_hh, b_ih, b_hh, Wp, bp,
        featw, out + (size_t)BATCH * 8192);
    recon_kernel<<<BATCH, 256, 0, stream>>>(featw, out);
}

// Round 6
// 131.184 us; speedup vs baseline: 2.1035x; 1.0246x over previous
//
#include <hip/hip_runtime.h>

#define NQ 6
#define HID 32
#define SNAPS 16
#define BATCH 1024
#define FSTRIDE 24       // floats per feature vector
#define FTOT 384         // 16 * 24
#define KSTR 24          // K-matrix LDS stride (16B-aligned, <=2-way conflicts = free)
#define KF   192         // per-f block: 8 cols/rows x 24

typedef float vfloat4 __attribute__((ext_vector_type(4)));   // for nontemporal stores

__device__ __forceinline__ float sigm_f(float x) { return 1.0f / (1.0f + __expf(-x)); }
__device__ __forceinline__ float tanh_f(float x) { return 1.0f - 2.0f / (__expf(2.0f * x) + 1.0f); }

__device__ __forceinline__ void rc_entry(float g, float b0, float b1, float b2,
                                         int i, int j, float& re, float& im) {
    // rc = (I + 3*shadow*B)/2, B = b0*sx + b1*sy + b2*sz ; g = 1.5*shadow
    if (i == j) { re = 0.5f + (i ? -g * b2 : g * b2); im = 0.0f; }
    else        { re = g * b0;  im = (i ? g * b1 : -g * b1); }
}

// One block per batch element. Phase 1: waves 0-1 run the 15-step LSTM
// (1 gate row per lane), feats accumulate in LDS. Phase 2: all 4 waves build
// KA/KB and do the rank-16 complex outer-product accumulation.
__global__ __launch_bounds__(256, 2)   // cap 128 VGPR (no spill); <=128 => 4 waves/SIMD
void fused_kernel(const float* __restrict__ snapshot,   // (B,6)
                  const float* __restrict__ bcv,        // (B,6,3)
                  const float* __restrict__ h0,         // (B,32)
                  const float* __restrict__ c0,         // (B,32)
                  const float* __restrict__ W_ih,       // (128,24)
                  const float* __restrict__ W_hh,       // (128,32)
                  const float* __restrict__ b_ih,       // (128)
                  const float* __restrict__ b_hh,       // (128)
                  const float* __restrict__ Wp,         // (6,32,3)
                  const float* __restrict__ bp,         // (6,3)
                  float* __restrict__ out,              // (B,2,64,64)
                  float* __restrict__ out_tail)         // (B,6,3)
{
    __shared__ __align__(16) float sKA[16 * KF];   // 3072
    __shared__ __align__(16) float sKB[16 * KF];   // 3072
    __shared__ __align__(16) float feat[FTOT];     // 384
    __shared__ __align__(16) float sh[HID];        // 32
    __shared__ __align__(16) float sg[128];        // gate pre-activations

    const int b = blockIdx.x;
    const int t = threadIdx.x;

    // ---- phase-1 register state ----
    float4 wih[6], whh[8];
    float bias = 0.0f;
    if (t < 128) {
        const float4* p = (const float4*)(W_ih + t * 24);
        #pragma unroll
        for (int k = 0; k < 6; ++k) wih[k] = p[k];
        const float4* q = (const float4*)(W_hh + t * 32);
        #pragma unroll
        for (int k = 0; k < 8; ++k) whh[k] = q[k];
        bias = b_ih[t] + b_hh[t];
    }
    float wp[32];
    float bpv = 0.0f, c = 0.0f;
    if (t < 18) {
        int q = t / 3, s = t - 3 * q;
        #pragma unroll
        for (int k = 0; k < 32; ++k) wp[k] = Wp[q * 96 + 3 * k + s];
        bpv = bp[t];
    }
    if (t < 32) { c = c0[b * 32 + t]; sh[t] = h0[b * 32 + t]; }
    if (t < 24) feat[t] = (t < 6) ? snapshot[b * 6 + t] : bcv[b * 18 + (t - 6)];
    __syncthreads();

    // ---- LSTM chain: 15 steps, 2 block barriers/step ----
    for (int step = 0; step < SNAPS - 1; ++step) {
        if (t < 128) {
            const float4* x4 = (const float4*)(feat + step * FSTRIDE);  // broadcast
            const float4* h4 = (const float4*)sh;
            float ga = bias, gb = 0.0f;
            #pragma unroll
            for (int k = 0; k < 6; ++k) {
                float4 xq = x4[k];
                ga += xq.x * wih[k].x + xq.y * wih[k].y;
                gb += xq.z * wih[k].z + xq.w * wih[k].w;
            }
            #pragma unroll
            for (int k = 0; k < 8; ++k) {
                float4 hq = h4[k];
                ga += hq.x * whh[k].x + hq.y * whh[k].y;
                gb += hq.z * whh[k].z + hq.w * whh[k].w;
            }
            sg[t] = ga + gb;
        }
        __syncthreads();

        if (t < 64) {   // wave 0 only: activation + projection + softmax
            if (t < 32) {
                float gi = sg[t], gf = sg[32 + t], gg = sg[64 + t], go = sg[96 + t];
                c = sigm_f(gf) * c + sigm_f(gi) * tanh_f(gg);
                sh[t] = sigm_f(go) * tanh_f(c);
            }
            __builtin_amdgcn_wave_barrier();   // order in-wave DS: sh write -> reads below
            // projection: lanes 0..17 (others compute garbage, discarded)
            float logit = bpv;
            const float4* h4b = (const float4*)sh;
            #pragma unroll
            for (int k = 0; k < 8; ++k) {
                float4 hq = h4b[k];
                logit += hq.x * wp[4 * k] + hq.y * wp[4 * k + 1]
                       + hq.z * wp[4 * k + 2] + hq.w * wp[4 * k + 3];
            }
            int q3 = 3 * (t < 6 ? t : 0);
            float l0 = __shfl(logit, q3), l1 = __shfl(logit, q3 + 1), l2 = __shfl(logit, q3 + 2);
            if (t < 6) {
                float m = fmaxf(l0, fmaxf(l1, l2));
                float e0 = __expf(l0 - m), e1 = __expf(l1 - m), e2 = __expf(l2 - m);
                float inv = 1.0f / (e0 + e1 + e2);
                float p0 = e0 * inv, p1 = e1 * inv, p2 = e2 * inv;
                float snap = p0 * p0 + p1 * p1 + p2 * p2;  // tr(M rho Mdag)=sum p^2 (rho unused)
                float* fd = feat + (step + 1) * FSTRIDE;
                fd[t] = snap;
                fd[6 + 3 * t]     = p0;
                fd[6 + 3 * t + 1] = p1;
                fd[6 + 3 * t + 2] = p2;
            }
        }
        __syncthreads();
    }

    // ---- tail output: bv of last feature = final probs ----
    if (t < 18) out_tail[b * 18 + t] = feat[15 * FSTRIDE + 6 + t];

    // ---- build KA/KB: 2048 entries, 8 per thread ----
    for (int n = t; n < 2048; n += 256) {
        int f = n >> 7, r = n & 127;
        int half = r >> 6, a = r & 63;
        const float* fx = &feat[f * FSTRIDE];
        int i0 = (a >> 5) & 1, i1 = (a >> 4) & 1, i2 = (a >> 3) & 1;
        int j0 = (a >> 2) & 1, j1 = (a >> 1) & 1, j2 = a & 1;
        int q = 3 * half;
        float g0 = 1.5f * fx[q], g1 = 1.5f * fx[q + 1], g2 = 1.5f * fx[q + 2];
        const float* bb = fx + 6 + 3 * q;
        float r0, m0, r1, m1, r2, m2;
        rc_entry(g0, bb[0], bb[1], bb[2], i0, j0, r0, m0);
        rc_entry(g1, bb[3], bb[4], bb[5], i1, j1, r1, m1);
        rc_entry(g2, bb[6], bb[7], bb[8], i2, j2, r2, m2);
        float pr = r0 * r1 - m0 * m1, pi = r0 * m1 + m0 * r1;
        float qr = pr * r2 - pi * m2, qi = pr * m2 + pi * r2;
        int row = a >> 3, col = a & 7;
        if (half == 0) {
            // KA: col-major, rows grouped by parity (even at [0..7], odd at [8..15])
            int off = f * KF + col * KSTR + ((row & 1) ? (7 + row) : row);
            sKA[off] = qr; sKA[off + 1] = qi;
        } else {
            int off = f * KF + row * KSTR + 2 * col;
            sKB[off] = qr; sKB[off + 1] = qi;
        }
    }
    __syncthreads();

    // ---- accumulate: out[i][j] = (1/16) sum_f KA[i>>3][j>>3] * KB[i&7][j&7]
    // thread t: u=t&15, v=t>>4; i = v+16e (e<4), j = 4u+d (d<4)
    const int u = t & 15, v = t >> 4;
    const float* baseA = sKA + (u >> 1) * KSTR + 8 * (v >> 3);   // col jA, parity group
    const float* baseB = sKB + (v & 7) * KSTR + 8 * (u & 1);     // row iB, col group
    float accr[4][4], acci[4][4];
    #pragma unroll
    for (int e = 0; e < 4; ++e)
        #pragma unroll
        for (int d = 0; d < 4; ++d) { accr[e][d] = 0.0f; acci[e][d] = 0.0f; }

    #pragma unroll 2   // keep hoisted LDS loads within the 128-VGPR budget (no scratch!)
    for (int f = 0; f < SNAPS; ++f) {
        float4 A0 = *(const float4*)(baseA + f * KF);
        float4 A1 = *(const float4*)(baseA + f * KF + 4);
        float4 B0 = *(const float4*)(baseB + f * KF);
        float4 B1 = *(const float4*)(baseB + f * KF + 4);
        float ar[4] = {A0.x, A0.z, A1.x, A1.z};    // iA = 2e + (v>>3)
        float ai[4] = {A0.y, A0.w, A1.y, A1.w};
        float br[4] = {B0.x, B0.z, B1.x, B1.z};    // jB = 4(u&1) + d
        float bi[4] = {B0.y, B0.w, B1.y, B1.w};
        #pragma unroll
        for (int e = 0; e < 4; ++e)
            #pragma unroll
            for (int d = 0; d < 4; ++d) {
                accr[e][d] += ar[e] * br[d] - ai[e] * bi[d];
                acci[e][d] += ar[e] * bi[d] + ai[e] * br[d];
            }
    }

    const float s = 1.0f / 16.0f;
    float* outb = out + (size_t)b * 8192;
    #pragma unroll
    for (int e = 0; e < 4; ++e) {
        int i = v + 16 * e;
        vfloat4 r4 = { accr[e][0] * s, accr[e][1] * s, accr[e][2] * s, accr[e][3] * s };
        vfloat4 i4 = { acci[e][0] * s, acci[e][1] * s, acci[e][2] * s, acci[e][3] * s };
        __builtin_nontemporal_store(r4, (vfloat4*)(outb + i * 64 + 4 * u));
        __builtin_nontemporal_store(i4, (vfloat4*)(outb + 4096 + i * 64 + 4 * u));
    }
}

extern "C" void kernel_launch(void* const* d_in, const int* in_sizes, int n_in,
                              void* d_out, int out_size, void* d_ws, size_t ws_size,
                              hipStream_t stream) {
    const float* snapshot = (const float*)d_in[0];
    const float* bcv      = (const float*)d_in[1];
    // d_in[2] = rho — unused: tr(M rho M^dag) = (sum_s p_s^2) tr(rho), tr(rho)=1
    const float* h0       = (const float*)d_in[3];
    const float* c0       = (const float*)d_in[4];
    const float* W_ih     = (const float*)d_in[5];
    const float* W_hh     = (const float*)d_in[6];
    const float* b_ih     = (const float*)d_in[7];
    const float* b_hh     = (const float*)d_in[8];
    const float* Wp       = (const float*)d_in[9];
    const float* bp       = (const float*)d_in[10];
    // d_in[11], d_in[12] = basis_r, basis_i — folded into rc_entry
    float* out = (float*)d_out;

    fused_kernel<<<BATCH, 256, 0, stream>>>(
        snapshot, bcv, h0, c0, W_ih, W_hh, b_ih, b_hh, Wp, bp,
        out, out + (size_t)BATCH * 8192);
}